// Round 4
// baseline (398.272 us; speedup 1.0000x reference)
//
#include <hip/hip_runtime.h>

typedef __attribute__((ext_vector_type(8))) short short8_t;
typedef __attribute__((ext_vector_type(4))) float f32x4;

// ---------------- problem constants ----------------
#define N_ROWS   131072     // 32*64*64
#define DIM      64
#define NE       512
#define DECAYF   0.99f
#define OMDECAY  0.01f
#define EPSF     1e-5f
#define GAP_THR  0.02f

// ---------------- d_out offsets (floats) ----------------
#define Q_OFF    0            // 8388608
#define DIFF_OFF 8388608      // 1
#define IND_OFF  8388609      // 131072
#define CS_OFF   8519681      // 512
#define AVG_OFF  8520193      // 32768
#define EMB_OFF  8552961      // 32768

// ---------------- ws offsets (floats) ----------------
#define WS_ET      0            // 32768 : ET fp32 [code][dim]
#define WS_ENORM   32768        // 512   : ||E_j||^2 fp32
#define WS_EN64    33280        // 1024  : ||E_j||^2 fp64 (512 doubles)
#define WS_CSDIV   34304        // 512   : cs divisor
#define WS_DIFF    34816        // 1
#define WS_RCNT    34817        // 1 (int)
#define WS_IDX     34818        // 131072 (int)
#define WS_RLIST   165890       // 131072 (int)
#define WS_BH      296964       // 16384 floats: packed bf16 hi B-fragments
#define WS_BL      313348       // 16384 floats: packed bf16 lo B-fragments
#define WS_HIST    329732       // 512 (int)
#define WS_BINBASE 330244       // 512 (int)
#define WS_CURSOR  330756       // 512 (int)
#define WS_SORTED  331268       // 131072 (int)

__device__ __forceinline__ ushort f32_to_bf16_rn(float f) {
    unsigned u = __float_as_uint(f);
    unsigned r = (u + 0x7FFFu + ((u >> 16) & 1u)) >> 16;
    return (ushort)r;
}
__device__ __forceinline__ float bf16_to_f32(ushort h) {
    return __uint_as_float(((unsigned)h) << 16);
}

// ============================================================
// prep1: embed -> ET fp32; packed bf16 hi/lo B-fragments; zero accums+hist.
// grid 64 blocks (d) x 512 threads (c): coalesced embed read.
// ============================================================
__global__ __launch_bounds__(512) void prep1_kernel(const float* __restrict__ embed,
                                                    float* __restrict__ ws) {
    const int d = blockIdx.x;    // dim 0..63
    const int c = threadIdx.x;   // code 0..511
    float v = embed[d * NE + c];
    ws[WS_ET + c * DIM + d] = v;

    ushort hb = f32_to_bf16_rn(v);
    float  lf = v - bf16_to_f32(hb);
    ushort lb = f32_to_bf16_rn(lf);

    // fragment order: tile T=c>>4, n=c&15, kstep s=d>>5, k8=(d>>3)&3, j=d&7
    const int T  = c >> 4;
    const int n  = c & 15;
    const int s  = d >> 5;
    const int k8 = (d >> 3) & 3;
    const int j  = d & 7;
    const int l  = k8 * 16 + n;
    const int idx = (T * 2 + s) * 512 + l * 8 + j;
    ((ushort*)(ws + WS_BH))[idx] = hb;
    ((ushort*)(ws + WS_BL))[idx] = lb;

    if (d == 0 && c == 0) {
        ws[WS_DIFF] = 0.0f;
        ((int*)ws)[WS_RCNT] = 0;
    }
    if (d == 1) ((int*)ws)[WS_HIST + c] = 0;
}

// ============================================================
// prep2: enorm fp32 + fp64 from ET (coalesced). wave per code.
// ============================================================
__global__ __launch_bounds__(256) void prep2_kernel(float* __restrict__ ws) {
    const int jcode = blockIdx.x * 4 + (threadIdx.x >> 6);
    const int d     = threadIdx.x & 63;
    float v = ws[WS_ET + jcode * DIM + d];
    double sq = (double)v * (double)v;
    #pragma unroll
    for (int off = 32; off > 0; off >>= 1) sq += __shfl_down(sq, off, 64);
    if (d == 0) {
        ws[WS_ENORM + jcode] = (float)sq;
        ((double*)(ws + WS_EN64))[jcode] = sq;
    }
}

// ============================================================
// dist: MFMA bf16 3-term split + fused argmin/second-min.
// 256 threads = 4 waves; wave handles 32 rows x 512 codes.
// ============================================================
__global__ __launch_bounds__(256) void dist_kernel(const float* __restrict__ input,
                                                   float* __restrict__ ws) {
    const int tid  = threadIdx.x;
    const int lane = tid & 63;
    const int wv   = tid >> 6;
    const int r0   = blockIdx.x * 128 + wv * 32;
    const int n15  = lane & 15;
    const int koff = (lane >> 4) * 8;

    short8_t Ahi[2][2], Alo[2][2];
    #pragma unroll
    for (int sub = 0; sub < 2; sub++) {
        const float* rp = input + (size_t)(r0 + sub * 16 + n15) * DIM + koff;
        #pragma unroll
        for (int s = 0; s < 2; s++) {
            float4 x0 = *(const float4*)(rp + s * 32);
            float4 x1 = *(const float4*)(rp + s * 32 + 4);
            float xf[8] = {x0.x, x0.y, x0.z, x0.w, x1.x, x1.y, x1.z, x1.w};
            short8_t h, l;
            #pragma unroll
            for (int e = 0; e < 8; e++) {
                ushort hb = f32_to_bf16_rn(xf[e]);
                float  lf = xf[e] - bf16_to_f32(hb);
                ushort lb = f32_to_bf16_rn(lf);
                h[e] = (short)hb;
                l[e] = (short)lb;
            }
            Ahi[sub][s] = h;
            Alo[sub][s] = l;
        }
    }

    const ushort* bhp = (const ushort*)(ws + WS_BH) + lane * 8;
    const ushort* blp = (const ushort*)(ws + WS_BL) + lane * 8;

    float m1[8], m2[8];
    int   j1[8];
    #pragma unroll
    for (int i = 0; i < 8; i++) { m1[i] = 3.4e38f; m2[i] = 3.4e38f; j1[i] = 0; }

    #pragma unroll 2
    for (int T = 0; T < 32; T++) {
        short8_t Bh0 = *(const short8_t*)(bhp + T * 1024);
        short8_t Bh1 = *(const short8_t*)(bhp + T * 1024 + 512);
        short8_t Bl0 = *(const short8_t*)(blp + T * 1024);
        short8_t Bl1 = *(const short8_t*)(blp + T * 1024 + 512);

        f32x4 aa = {0.f, 0.f, 0.f, 0.f};
        f32x4 ab = {0.f, 0.f, 0.f, 0.f};
        aa = __builtin_amdgcn_mfma_f32_16x16x32_bf16(Ahi[0][0], Bh0, aa, 0, 0, 0);
        ab = __builtin_amdgcn_mfma_f32_16x16x32_bf16(Ahi[1][0], Bh0, ab, 0, 0, 0);
        aa = __builtin_amdgcn_mfma_f32_16x16x32_bf16(Alo[0][0], Bh0, aa, 0, 0, 0);
        ab = __builtin_amdgcn_mfma_f32_16x16x32_bf16(Alo[1][0], Bh0, ab, 0, 0, 0);
        aa = __builtin_amdgcn_mfma_f32_16x16x32_bf16(Ahi[0][0], Bl0, aa, 0, 0, 0);
        ab = __builtin_amdgcn_mfma_f32_16x16x32_bf16(Ahi[1][0], Bl0, ab, 0, 0, 0);
        aa = __builtin_amdgcn_mfma_f32_16x16x32_bf16(Ahi[0][1], Bh1, aa, 0, 0, 0);
        ab = __builtin_amdgcn_mfma_f32_16x16x32_bf16(Ahi[1][1], Bh1, ab, 0, 0, 0);
        aa = __builtin_amdgcn_mfma_f32_16x16x32_bf16(Alo[0][1], Bh1, aa, 0, 0, 0);
        ab = __builtin_amdgcn_mfma_f32_16x16x32_bf16(Alo[1][1], Bh1, ab, 0, 0, 0);
        aa = __builtin_amdgcn_mfma_f32_16x16x32_bf16(Ahi[0][1], Bl1, aa, 0, 0, 0);
        ab = __builtin_amdgcn_mfma_f32_16x16x32_bf16(Ahi[1][1], Bl1, ab, 0, 0, 0);

        const float en = ws[WS_ENORM + T * 16 + n15];
        const int   jc = T * 16 + n15;
        #pragma unroll
        for (int q = 0; q < 4; q++) {
            float da = fmaf(-2.0f, aa[q], en);
            m2[q]    = fminf(m2[q], fmaxf(m1[q], da));
            j1[q]    = (da < m1[q]) ? jc : j1[q];
            m1[q]    = fminf(m1[q], da);
            float db = fmaf(-2.0f, ab[q], en);
            m2[q+4]  = fminf(m2[q+4], fmaxf(m1[q+4], db));
            j1[q+4]  = (db < m1[q+4]) ? jc : j1[q+4];
            m1[q+4]  = fminf(m1[q+4], db);
        }
    }

    #pragma unroll
    for (int off = 1; off < 16; off <<= 1) {
        #pragma unroll
        for (int i = 0; i < 8; i++) {
            float b1 = __shfl_xor(m1[i], off, 64);
            float b2 = __shfl_xor(m2[i], off, 64);
            int   bj = __shfl_xor(j1[i], off, 64);
            float a1 = m1[i];
            float nm2 = fminf(fminf(m2[i], b2), fmaxf(a1, b1));
            bool takeB = (b1 < a1) || (b1 == a1 && bj < j1[i]);
            m1[i] = takeB ? b1 : a1;
            j1[i] = takeB ? bj : j1[i];
            m2[i] = nm2;
        }
    }

    if (n15 == 0) {
        #pragma unroll
        for (int i = 0; i < 8; i++) {
            int sub = i >> 2, q = i & 3;
            int r = r0 + sub * 16 + (lane >> 4) * 4 + q;
            ((int*)ws)[WS_IDX + r] = j1[i];
            if (m2[i] - m1[i] < GAP_THR) {
                int pos = atomicAdd((int*)ws + WS_RCNT, 1);
                ((int*)ws)[WS_RLIST + pos] = r;
            }
        }
    }
}

// ============================================================
// refine: fp64 re-resolution of near-tie rows.
// ============================================================
__global__ __launch_bounds__(64) void refine_kernel(const float* __restrict__ input,
                                                    float* __restrict__ ws) {
    __shared__ float rowf[DIM];
    const int cnt  = ((const int*)ws)[WS_RCNT];
    const int lane = threadIdx.x;
    const double* en64 = (const double*)(ws + WS_EN64);
    for (int ii = blockIdx.x; ii < cnt; ii += 512) {
        const int r = ((const int*)ws)[WS_RLIST + ii];
        __syncthreads();
        rowf[lane] = input[(size_t)r * DIM + lane];
        __syncthreads();
        double bd = 1e300;
        int    bj = 0x7fffffff;
        for (int kk = 0; kk < 8; kk++) {
            int j = kk * 64 + lane;
            const float* ep = ws + WS_ET + j * DIM;
            double s = 0.0;
            #pragma unroll 8
            for (int d = 0; d < DIM; d++)
                s = fma((double)ep[d], (double)rowf[d], s);
            double dist = en64[j] - 2.0 * s;
            if (dist < bd || (dist == bd && j < bj)) { bd = dist; bj = j; }
        }
        #pragma unroll
        for (int off = 32; off > 0; off >>= 1) {
            double od = __shfl_down(bd, off, 64);
            int    oj = __shfl_down(bj, off, 64);
            if (od < bd || (od == bd && oj < bj)) { bd = od; bj = oj; }
        }
        if (lane == 0) ((int*)ws)[WS_IDX + r] = bj;
    }
}

// ============================================================
// quantize: gather + quantize write + diff + embed_ind + LDS histogram.
// 512 blocks x 256 threads; block owns 256 rows. No big LDS -> high occupancy.
// ============================================================
__global__ __launch_bounds__(256) void quantize_kernel(const float* __restrict__ input,
                                                       float* __restrict__ ws,
                                                       float* __restrict__ out) {
    __shared__ int hist[NE];
    __shared__ float wsum[4];
    const int tid = threadIdx.x;
    for (int e = tid; e < NE; e += 256) hist[e] = 0;
    __syncthreads();

    const int lane = tid & 63;
    const int wv   = tid >> 6;
    const int rsub = lane >> 4;        // 0..3
    const int d4   = (lane & 15) * 4;  // dim quad
    const int base = blockIdx.x * 256;
    float dacc = 0.0f;

    #pragma unroll 4
    for (int it = 0; it < 16; it++) {
        int r = base + (it * 4 + wv) * 4 + rsub;
        int j = ((const int*)ws)[WS_IDX + r];
        float4 in4 = *(const float4*)(input + (size_t)r * DIM + d4);
        float4 q4  = *(const float4*)(ws + WS_ET + j * DIM + d4);
        *(float4*)(out + Q_OFF + (size_t)r * DIM + d4) = q4;
        float dx = q4.x - in4.x, dy = q4.y - in4.y, dz = q4.z - in4.z, dw = q4.w - in4.w;
        dacc = fmaf(dx, dx, fmaf(dy, dy, fmaf(dz, dz, fmaf(dw, dw, dacc))));
        if ((lane & 15) == 0) {
            atomicAdd(&hist[j], 1);
            out[IND_OFF + r] = (float)j;
        }
    }
    __syncthreads();

    for (int e = tid; e < NE; e += 256) {
        int h = hist[e];
        if (h) atomicAdd((int*)ws + WS_HIST + e, h);
    }

    #pragma unroll
    for (int off = 32; off > 0; off >>= 1) dacc += __shfl_down(dacc, off, 64);
    if (lane == 0) wsum[wv] = dacc;
    __syncthreads();
    if (tid == 0)
        atomicAdd(&ws[WS_DIFF], wsum[0] + wsum[1] + wsum[2] + wsum[3]);
}

// ============================================================
// scan (1 block x 512): exclusive scan of hist -> binbase/cursor;
// fused exact new_cluster_size EMA.
// ============================================================
__global__ __launch_bounds__(512) void scan_kernel(const float* __restrict__ cluster_size,
                                                   float* __restrict__ ws,
                                                   float* __restrict__ out) {
    __shared__ int wsums[8];
    const int t    = threadIdx.x;
    const int lane = t & 63;
    const int wv   = t >> 6;
    const int v    = ((const int*)ws)[WS_HIST + t];
    int x = v;
    #pragma unroll
    for (int off = 1; off < 64; off <<= 1) {
        int y = __shfl_up(x, off, 64);
        if (lane >= off) x += y;
    }
    if (lane == 63) wsums[wv] = x;
    __syncthreads();
    int add = 0;
    for (int w = 0; w < wv; w++) add += wsums[w];
    const int excl = x + add - v;
    ((int*)ws)[WS_BINBASE + t] = excl;
    ((int*)ws)[WS_CURSOR + t]  = excl;
    out[CS_OFF + t] = fmaf(cluster_size[t], DECAYF, OMDECAY * (float)v);
}

// ============================================================
// place: counting-sort scatter of row ids into bins.
// ============================================================
__global__ __launch_bounds__(256) void place_kernel(float* __restrict__ ws) {
    const int r = blockIdx.x * 256 + threadIdx.x;
    const int j = ((const int*)ws)[WS_IDX + r];
    const int pos = atomicAdd((int*)ws + WS_CURSOR + j, 1);
    ((int*)ws)[WS_SORTED + pos] = r;
}

// ============================================================
// sum: block per code; wave reads one row (64 lanes = 256B, coalesced);
// unroll-4 for MLP; cross-wave LDS reduce; fused new_embed_avg EMA.
// ============================================================
__global__ __launch_bounds__(256) void sum_kernel(const float* __restrict__ input,
                                                  const float* __restrict__ embed_avg,
                                                  const float* __restrict__ ws,
                                                  float* __restrict__ out) {
    __shared__ float part[4][DIM];
    const int j    = blockIdx.x;
    const int base = ((const int*)ws)[WS_BINBASE + j];
    const int cnt  = ((const int*)ws)[WS_HIST + j];
    const int lane = threadIdx.x & 63;
    const int wv   = threadIdx.x >> 6;
    const int* rows = (const int*)ws + WS_SORTED + base;

    float acc = 0.0f;
    int i = wv;
    for (; i + 12 < cnt; i += 16) {
        int r0 = rows[i], r1 = rows[i + 4], r2 = rows[i + 8], r3 = rows[i + 12];
        float a = input[(size_t)r0 * DIM + lane];
        float b = input[(size_t)r1 * DIM + lane];
        float c = input[(size_t)r2 * DIM + lane];
        float d = input[(size_t)r3 * DIM + lane];
        acc += ((a + b) + (c + d));
    }
    for (; i < cnt; i += 4)
        acc += input[(size_t)rows[i] * DIM + lane];

    part[wv][lane] = acc;
    __syncthreads();
    if (wv == 0) {
        float s = (part[0][lane] + part[1][lane]) + (part[2][lane] + part[3][lane]);
        out[AVG_OFF + lane * NE + j] = fmaf(embed_avg[lane * NE + j], DECAYF, OMDECAY * s);
    }
}

// ============================================================
// finalize1 (1 block): n, cs divisor, diff.
// ============================================================
__global__ __launch_bounds__(512) void finalize1_kernel(float* __restrict__ ws,
                                                        float* __restrict__ out) {
    __shared__ float red[8];
    const int t = threadIdx.x;
    float v = out[CS_OFF + t];
    float s = v;
    #pragma unroll
    for (int off = 32; off > 0; off >>= 1) s += __shfl_down(s, off, 64);
    if ((t & 63) == 0) red[t >> 6] = s;
    __syncthreads();
    float n = red[0] + red[1] + red[2] + red[3] + red[4] + red[5] + red[6] + red[7];
    ws[WS_CSDIV + t] = (v + EPSF) / (n + (float)NE * EPSF) * n;
    if (t == 0) out[DIFF_OFF] = ws[WS_DIFF] * (1.0f / 8388608.0f);
}

// ============================================================
// finalize2: new_embed = new_embed_avg / cs  (grid-wide).
// ============================================================
__global__ __launch_bounds__(512) void finalize2_kernel(const float* __restrict__ ws,
                                                        float* __restrict__ out) {
    int e = blockIdx.x * 512 + threadIdx.x;
    out[EMB_OFF + e] = out[AVG_OFF + e] / ws[WS_CSDIV + (e & (NE - 1))];
}

// ============================================================
extern "C" void kernel_launch(void* const* d_in, const int* in_sizes, int n_in,
                              void* d_out, int out_size, void* d_ws, size_t ws_size,
                              hipStream_t stream) {
    const float* input        = (const float*)d_in[0];
    const float* embed        = (const float*)d_in[1];
    const float* cluster_size = (const float*)d_in[2];
    const float* embed_avg    = (const float*)d_in[3];
    float* out = (float*)d_out;
    float* ws  = (float*)d_ws;

    prep1_kernel<<<64, 512, 0, stream>>>(embed, ws);
    prep2_kernel<<<128, 256, 0, stream>>>(ws);
    dist_kernel<<<N_ROWS / 128, 256, 0, stream>>>(input, ws);
    refine_kernel<<<512, 64, 0, stream>>>(input, ws);
    quantize_kernel<<<512, 256, 0, stream>>>(input, ws, out);
    scan_kernel<<<1, 512, 0, stream>>>(cluster_size, ws, out);
    place_kernel<<<N_ROWS / 256, 256, 0, stream>>>(ws);
    sum_kernel<<<NE, 256, 0, stream>>>(input, embed_avg, ws, out);
    finalize1_kernel<<<1, 512, 0, stream>>>(ws, out);
    finalize2_kernel<<<64, 512, 0, stream>>>(ws, out);
}

// Round 5
// 138.670 us; speedup vs baseline: 2.8721x; 2.8721x over previous
//
#include <hip/hip_runtime.h>

typedef __attribute__((ext_vector_type(8))) short short8_t;
typedef __attribute__((ext_vector_type(4))) float f32x4;

// ---------------- problem constants ----------------
#define N_ROWS   131072     // 32*64*64
#define DIM      64
#define NE       512
#define DECAYF   0.99f
#define OMDECAY  0.01f
#define EPSF     1e-5f
#define GAP_THR  0.02f

// ---------------- d_out offsets (floats) ----------------
#define Q_OFF    0            // 8388608
#define DIFF_OFF 8388608      // 1
#define IND_OFF  8388609      // 131072
#define CS_OFF   8519681      // 512
#define AVG_OFF  8520193      // 32768
#define EMB_OFF  8552961      // 32768

// ---------------- ws offsets (floats) ----------------
#define WS_ET      0            // 32768 : ET fp32 [code][dim]
#define WS_ENORM   32768        // 512   : ||E_j||^2 fp32
#define WS_EN64    33280        // 1024  : ||E_j||^2 fp64 (512 doubles)
#define WS_CSDIV   34304        // 512   : cs divisor
#define WS_DIFF    34816        // 1
#define WS_RCNT    34817        // 1 (int)
#define WS_IDX     34818        // 131072 (int)
#define WS_RLIST   165890       // 131072 (int)
#define WS_BH      296964       // 16384 floats: packed bf16 hi B-fragments
#define WS_BL      313348       // 16384 floats: packed bf16 lo B-fragments
#define WS_HIST    329732       // 512 (int)
#define WS_BINBASE 330244       // 512 (int)
#define WS_CURSOR  330756       // 512 (int)
#define WS_SORTED  331268       // 131072 (int)
#define WS_ACCUM   462340       // 32768 : embed_sum accumulator [code][dim]

__device__ __forceinline__ ushort f32_to_bf16_rn(float f) {
    unsigned u = __float_as_uint(f);
    unsigned r = (u + 0x7FFFu + ((u >> 16) & 1u)) >> 16;
    return (ushort)r;
}
__device__ __forceinline__ float bf16_to_f32(ushort h) {
    return __uint_as_float(((unsigned)h) << 16);
}

// ============================================================
// prep1: embed -> ET fp32; packed bf16 hi/lo B-fragments; zero accums.
// grid 64 blocks (d) x 512 threads (c): coalesced embed read.
// ============================================================
__global__ __launch_bounds__(512) void prep1_kernel(const float* __restrict__ embed,
                                                    float* __restrict__ ws) {
    const int d = blockIdx.x;    // dim 0..63
    const int c = threadIdx.x;   // code 0..511
    float v = embed[d * NE + c];
    ws[WS_ET + c * DIM + d] = v;

    ushort hb = f32_to_bf16_rn(v);
    float  lf = v - bf16_to_f32(hb);
    ushort lb = f32_to_bf16_rn(lf);

    // fragment order: tile T=c>>4, n=c&15, kstep s=d>>5, k8=(d>>3)&3, j=d&7
    const int T  = c >> 4;
    const int n  = c & 15;
    const int s  = d >> 5;
    const int k8 = (d >> 3) & 3;
    const int j  = d & 7;
    const int l  = k8 * 16 + n;
    const int idx = (T * 2 + s) * 512 + l * 8 + j;
    ((ushort*)(ws + WS_BH))[idx] = hb;
    ((ushort*)(ws + WS_BL))[idx] = lb;

    if (d == 0 && c == 0) {
        ws[WS_DIFF] = 0.0f;
        ((int*)ws)[WS_RCNT] = 0;
    }
    if (d == 1) ((int*)ws)[WS_HIST + c] = 0;
    // zero the embed_sum accumulator (one element per thread: 64*512 = 32768)
    ws[WS_ACCUM + blockIdx.x * 512 + threadIdx.x] = 0.0f;
}

// ============================================================
// prep2: enorm fp32 + fp64 from ET (coalesced). wave per code.
// ============================================================
__global__ __launch_bounds__(256) void prep2_kernel(float* __restrict__ ws) {
    const int jcode = blockIdx.x * 4 + (threadIdx.x >> 6);
    const int d     = threadIdx.x & 63;
    float v = ws[WS_ET + jcode * DIM + d];
    double sq = (double)v * (double)v;
    #pragma unroll
    for (int off = 32; off > 0; off >>= 1) sq += __shfl_down(sq, off, 64);
    if (d == 0) {
        ws[WS_ENORM + jcode] = (float)sq;
        ((double*)(ws + WS_EN64))[jcode] = sq;
    }
}

// ============================================================
// dist: MFMA bf16 3-term split + fused argmin/second-min.
// 256 threads = 4 waves; wave handles 32 rows x 512 codes.
// ============================================================
__global__ __launch_bounds__(256) void dist_kernel(const float* __restrict__ input,
                                                   float* __restrict__ ws) {
    const int tid  = threadIdx.x;
    const int lane = tid & 63;
    const int wv   = tid >> 6;
    const int r0   = blockIdx.x * 128 + wv * 32;
    const int n15  = lane & 15;
    const int koff = (lane >> 4) * 8;

    short8_t Ahi[2][2], Alo[2][2];
    #pragma unroll
    for (int sub = 0; sub < 2; sub++) {
        const float* rp = input + (size_t)(r0 + sub * 16 + n15) * DIM + koff;
        #pragma unroll
        for (int s = 0; s < 2; s++) {
            float4 x0 = *(const float4*)(rp + s * 32);
            float4 x1 = *(const float4*)(rp + s * 32 + 4);
            float xf[8] = {x0.x, x0.y, x0.z, x0.w, x1.x, x1.y, x1.z, x1.w};
            short8_t h, l;
            #pragma unroll
            for (int e = 0; e < 8; e++) {
                ushort hb = f32_to_bf16_rn(xf[e]);
                float  lf = xf[e] - bf16_to_f32(hb);
                ushort lb = f32_to_bf16_rn(lf);
                h[e] = (short)hb;
                l[e] = (short)lb;
            }
            Ahi[sub][s] = h;
            Alo[sub][s] = l;
        }
    }

    const ushort* bhp = (const ushort*)(ws + WS_BH) + lane * 8;
    const ushort* blp = (const ushort*)(ws + WS_BL) + lane * 8;

    float m1[8], m2[8];
    int   j1[8];
    #pragma unroll
    for (int i = 0; i < 8; i++) { m1[i] = 3.4e38f; m2[i] = 3.4e38f; j1[i] = 0; }

    #pragma unroll 2
    for (int T = 0; T < 32; T++) {
        short8_t Bh0 = *(const short8_t*)(bhp + T * 1024);
        short8_t Bh1 = *(const short8_t*)(bhp + T * 1024 + 512);
        short8_t Bl0 = *(const short8_t*)(blp + T * 1024);
        short8_t Bl1 = *(const short8_t*)(blp + T * 1024 + 512);

        f32x4 aa = {0.f, 0.f, 0.f, 0.f};
        f32x4 ab = {0.f, 0.f, 0.f, 0.f};
        aa = __builtin_amdgcn_mfma_f32_16x16x32_bf16(Ahi[0][0], Bh0, aa, 0, 0, 0);
        ab = __builtin_amdgcn_mfma_f32_16x16x32_bf16(Ahi[1][0], Bh0, ab, 0, 0, 0);
        aa = __builtin_amdgcn_mfma_f32_16x16x32_bf16(Alo[0][0], Bh0, aa, 0, 0, 0);
        ab = __builtin_amdgcn_mfma_f32_16x16x32_bf16(Alo[1][0], Bh0, ab, 0, 0, 0);
        aa = __builtin_amdgcn_mfma_f32_16x16x32_bf16(Ahi[0][0], Bl0, aa, 0, 0, 0);
        ab = __builtin_amdgcn_mfma_f32_16x16x32_bf16(Ahi[1][0], Bl0, ab, 0, 0, 0);
        aa = __builtin_amdgcn_mfma_f32_16x16x32_bf16(Ahi[0][1], Bh1, aa, 0, 0, 0);
        ab = __builtin_amdgcn_mfma_f32_16x16x32_bf16(Ahi[1][1], Bh1, ab, 0, 0, 0);
        aa = __builtin_amdgcn_mfma_f32_16x16x32_bf16(Alo[0][1], Bh1, aa, 0, 0, 0);
        ab = __builtin_amdgcn_mfma_f32_16x16x32_bf16(Alo[1][1], Bh1, ab, 0, 0, 0);
        aa = __builtin_amdgcn_mfma_f32_16x16x32_bf16(Ahi[0][1], Bl1, aa, 0, 0, 0);
        ab = __builtin_amdgcn_mfma_f32_16x16x32_bf16(Ahi[1][1], Bl1, ab, 0, 0, 0);

        const float en = ws[WS_ENORM + T * 16 + n15];
        const int   jc = T * 16 + n15;
        #pragma unroll
        for (int q = 0; q < 4; q++) {
            float da = fmaf(-2.0f, aa[q], en);
            m2[q]    = fminf(m2[q], fmaxf(m1[q], da));
            j1[q]    = (da < m1[q]) ? jc : j1[q];
            m1[q]    = fminf(m1[q], da);
            float db = fmaf(-2.0f, ab[q], en);
            m2[q+4]  = fminf(m2[q+4], fmaxf(m1[q+4], db));
            j1[q+4]  = (db < m1[q+4]) ? jc : j1[q+4];
            m1[q+4]  = fminf(m1[q+4], db);
        }
    }

    #pragma unroll
    for (int off = 1; off < 16; off <<= 1) {
        #pragma unroll
        for (int i = 0; i < 8; i++) {
            float b1 = __shfl_xor(m1[i], off, 64);
            float b2 = __shfl_xor(m2[i], off, 64);
            int   bj = __shfl_xor(j1[i], off, 64);
            float a1 = m1[i];
            float nm2 = fminf(fminf(m2[i], b2), fmaxf(a1, b1));
            bool takeB = (b1 < a1) || (b1 == a1 && bj < j1[i]);
            m1[i] = takeB ? b1 : a1;
            j1[i] = takeB ? bj : j1[i];
            m2[i] = nm2;
        }
    }

    if (n15 == 0) {
        #pragma unroll
        for (int i = 0; i < 8; i++) {
            int sub = i >> 2, q = i & 3;
            int r = r0 + sub * 16 + (lane >> 4) * 4 + q;
            ((int*)ws)[WS_IDX + r] = j1[i];
            if (m2[i] - m1[i] < GAP_THR) {
                int pos = atomicAdd((int*)ws + WS_RCNT, 1);
                ((int*)ws)[WS_RLIST + pos] = r;
            }
        }
    }
}

// ============================================================
// refine: fp64 re-resolution of near-tie rows.
// ============================================================
__global__ __launch_bounds__(64) void refine_kernel(const float* __restrict__ input,
                                                    float* __restrict__ ws) {
    __shared__ float rowf[DIM];
    const int cnt  = ((const int*)ws)[WS_RCNT];
    const int lane = threadIdx.x;
    const double* en64 = (const double*)(ws + WS_EN64);
    for (int ii = blockIdx.x; ii < cnt; ii += 512) {
        const int r = ((const int*)ws)[WS_RLIST + ii];
        __syncthreads();
        rowf[lane] = input[(size_t)r * DIM + lane];
        __syncthreads();
        double bd = 1e300;
        int    bj = 0x7fffffff;
        for (int kk = 0; kk < 8; kk++) {
            int j = kk * 64 + lane;
            const float* ep = ws + WS_ET + j * DIM;
            double s = 0.0;
            #pragma unroll 8
            for (int d = 0; d < DIM; d++)
                s = fma((double)ep[d], (double)rowf[d], s);
            double dist = en64[j] - 2.0 * s;
            if (dist < bd || (dist == bd && j < bj)) { bd = dist; bj = j; }
        }
        #pragma unroll
        for (int off = 32; off > 0; off >>= 1) {
            double od = __shfl_down(bd, off, 64);
            int    oj = __shfl_down(bj, off, 64);
            if (od < bd || (od == bd && oj < bj)) { bd = od; bj = oj; }
        }
        if (lane == 0) ((int*)ws)[WS_IDX + r] = bj;
    }
}

// ============================================================
// quantize: gather + quantize write + diff + embed_ind + LDS histogram.
// 512 blocks x 256 threads; block owns 256 rows.
// ============================================================
__global__ __launch_bounds__(256) void quantize_kernel(const float* __restrict__ input,
                                                       float* __restrict__ ws,
                                                       float* __restrict__ out) {
    __shared__ int hist[NE];
    __shared__ float wsum[4];
    const int tid = threadIdx.x;
    for (int e = tid; e < NE; e += 256) hist[e] = 0;
    __syncthreads();

    const int lane = tid & 63;
    const int wv   = tid >> 6;
    const int rsub = lane >> 4;        // 0..3
    const int d4   = (lane & 15) * 4;  // dim quad
    const int base = blockIdx.x * 256;
    float dacc = 0.0f;

    #pragma unroll 4
    for (int it = 0; it < 16; it++) {
        int r = base + (it * 4 + wv) * 4 + rsub;
        int j = ((const int*)ws)[WS_IDX + r];
        float4 in4 = *(const float4*)(input + (size_t)r * DIM + d4);
        float4 q4  = *(const float4*)(ws + WS_ET + j * DIM + d4);
        *(float4*)(out + Q_OFF + (size_t)r * DIM + d4) = q4;
        float dx = q4.x - in4.x, dy = q4.y - in4.y, dz = q4.z - in4.z, dw = q4.w - in4.w;
        dacc = fmaf(dx, dx, fmaf(dy, dy, fmaf(dz, dz, fmaf(dw, dw, dacc))));
        if ((lane & 15) == 0) {
            atomicAdd(&hist[j], 1);
            out[IND_OFF + r] = (float)j;
        }
    }
    __syncthreads();

    for (int e = tid; e < NE; e += 256) {
        int h = hist[e];
        if (h) atomicAdd((int*)ws + WS_HIST + e, h);
    }

    #pragma unroll
    for (int off = 32; off > 0; off >>= 1) dacc += __shfl_down(dacc, off, 64);
    if (lane == 0) wsum[wv] = dacc;
    __syncthreads();
    if (tid == 0)
        atomicAdd(&ws[WS_DIFF], wsum[0] + wsum[1] + wsum[2] + wsum[3]);
}

// ============================================================
// scan (1 block x 512): exclusive scan of hist -> binbase/cursor;
// fused exact new_cluster_size EMA.
// ============================================================
__global__ __launch_bounds__(512) void scan_kernel(const float* __restrict__ cluster_size,
                                                   float* __restrict__ ws,
                                                   float* __restrict__ out) {
    __shared__ int wsums[8];
    const int t    = threadIdx.x;
    const int lane = t & 63;
    const int wv   = t >> 6;
    const int v    = ((const int*)ws)[WS_HIST + t];
    int x = v;
    #pragma unroll
    for (int off = 1; off < 64; off <<= 1) {
        int y = __shfl_up(x, off, 64);
        if (lane >= off) x += y;
    }
    if (lane == 63) wsums[wv] = x;
    __syncthreads();
    int add = 0;
    for (int w = 0; w < wv; w++) add += wsums[w];
    const int excl = x + add - v;
    ((int*)ws)[WS_BINBASE + t] = excl;
    ((int*)ws)[WS_CURSOR + t]  = excl;
    out[CS_OFF + t] = fmaf(cluster_size[t], DECAYF, OMDECAY * (float)v);
}

// ============================================================
// finalize1 (1 block): n, cs divisor, diff. (Runs after scan+quantize;
// does not touch AVG/EMB.)
// ============================================================
__global__ __launch_bounds__(512) void finalize1_kernel(float* __restrict__ ws,
                                                        float* __restrict__ out) {
    __shared__ float red[8];
    const int t = threadIdx.x;
    float v = out[CS_OFF + t];
    float s = v;
    #pragma unroll
    for (int off = 32; off > 0; off >>= 1) s += __shfl_down(s, off, 64);
    if ((t & 63) == 0) red[t >> 6] = s;
    __syncthreads();
    float n = red[0] + red[1] + red[2] + red[3] + red[4] + red[5] + red[6] + red[7];
    ws[WS_CSDIV + t] = (v + EPSF) / (n + (float)NE * EPSF) * n;
    if (t == 0) out[DIFF_OFF] = ws[WS_DIFF] * (1.0f / 8388608.0f);
}

// ============================================================
// place: skew-proof counting-sort placement.
// Per-block LDS histogram -> ONE global cursor reservation per distinct
// bin per block -> LDS-cursor placement. 512 blocks x 256 threads.
// ============================================================
__global__ __launch_bounds__(256) void place_kernel(float* __restrict__ ws) {
    __shared__ int lhist[NE];
    __shared__ int lbase[NE];
    __shared__ int lcur[NE];
    const int tid  = threadIdx.x;
    const int base = blockIdx.x * 256;

    for (int e = tid; e < NE; e += 256) { lhist[e] = 0; lcur[e] = 0; }
    __syncthreads();

    const int r = base + tid;
    const int j = ((const int*)ws)[WS_IDX + r];
    atomicAdd(&lhist[j], 1);
    __syncthreads();

    for (int e = tid; e < NE; e += 256)
        if (lhist[e]) lbase[e] = atomicAdd((int*)ws + WS_CURSOR + e, lhist[e]);
    __syncthreads();

    const int pos = lbase[j] + atomicAdd(&lcur[j], 1);
    ((int*)ws)[WS_SORTED + pos] = r;
}

// ============================================================
// sum: skew-proof segment-sum over the sorted row list.
// 2048 blocks x 1 wave; each wave owns 64 consecutive sorted slots.
// Row-ids/bin-ids preloaded into lanes, broadcast by shuffle; input rows
// gathered 4-at-a-time (independent loads); running accumulator flushed
// on bin transition via coalesced float atomics into accum[j][d].
// ============================================================
__global__ __launch_bounds__(64) void sum_kernel(const float* __restrict__ input,
                                                 float* __restrict__ ws) {
    const int lane = threadIdx.x;
    const int i0   = blockIdx.x * 64;

    const int rv = ((const int*)ws)[WS_SORTED + i0 + lane];
    const int jv = ((const int*)ws)[WS_IDX + rv];

    float acc  = 0.0f;
    int   jcur = __shfl(jv, 0, 64);

    for (int k = 0; k < 64; k += 4) {
        int r0 = __shfl(rv, k,     64);
        int r1 = __shfl(rv, k + 1, 64);
        int r2 = __shfl(rv, k + 2, 64);
        int r3 = __shfl(rv, k + 3, 64);
        float v0 = input[(size_t)r0 * DIM + lane];
        float v1 = input[(size_t)r1 * DIM + lane];
        float v2 = input[(size_t)r2 * DIM + lane];
        float v3 = input[(size_t)r3 * DIM + lane];
        int j0 = __shfl(jv, k,     64);
        int j1 = __shfl(jv, k + 1, 64);
        int j2 = __shfl(jv, k + 2, 64);
        int j3 = __shfl(jv, k + 3, 64);

        if (j0 != jcur) { atomicAdd(&ws[WS_ACCUM + jcur * DIM + lane], acc); acc = 0.0f; jcur = j0; }
        acc += v0;
        if (j1 != jcur) { atomicAdd(&ws[WS_ACCUM + jcur * DIM + lane], acc); acc = 0.0f; jcur = j1; }
        acc += v1;
        if (j2 != jcur) { atomicAdd(&ws[WS_ACCUM + jcur * DIM + lane], acc); acc = 0.0f; jcur = j2; }
        acc += v2;
        if (j3 != jcur) { atomicAdd(&ws[WS_ACCUM + jcur * DIM + lane], acc); acc = 0.0f; jcur = j3; }
        acc += v3;
    }
    atomicAdd(&ws[WS_ACCUM + jcur * DIM + lane], acc);
}

// ============================================================
// emaout: fused new_embed_avg + new_embed epilogue.
// e over 32768 output-major (d = e>>9, j = e&511): coalesced writes;
// accum reads are L2-hot gathers.
// ============================================================
__global__ __launch_bounds__(512) void emaout_kernel(const float* __restrict__ embed_avg,
                                                     const float* __restrict__ ws,
                                                     float* __restrict__ out) {
    const int e = blockIdx.x * 512 + threadIdx.x;
    const int d = e >> 9;
    const int j = e & (NE - 1);
    float s   = ws[WS_ACCUM + j * DIM + d];
    float avg = fmaf(embed_avg[e], DECAYF, OMDECAY * s);
    out[AVG_OFF + e] = avg;
    out[EMB_OFF + e] = avg / ws[WS_CSDIV + j];
}

// ============================================================
extern "C" void kernel_launch(void* const* d_in, const int* in_sizes, int n_in,
                              void* d_out, int out_size, void* d_ws, size_t ws_size,
                              hipStream_t stream) {
    const float* input        = (const float*)d_in[0];
    const float* embed        = (const float*)d_in[1];
    const float* cluster_size = (const float*)d_in[2];
    const float* embed_avg    = (const float*)d_in[3];
    float* out = (float*)d_out;
    float* ws  = (float*)d_ws;

    prep1_kernel<<<64, 512, 0, stream>>>(embed, ws);
    prep2_kernel<<<128, 256, 0, stream>>>(ws);
    dist_kernel<<<N_ROWS / 128, 256, 0, stream>>>(input, ws);
    refine_kernel<<<512, 64, 0, stream>>>(input, ws);
    quantize_kernel<<<512, 256, 0, stream>>>(input, ws, out);
    scan_kernel<<<1, 512, 0, stream>>>(cluster_size, ws, out);
    finalize1_kernel<<<1, 512, 0, stream>>>(ws, out);
    place_kernel<<<512, 256, 0, stream>>>(ws);
    sum_kernel<<<N_ROWS / 64, 64, 0, stream>>>(input, ws);
    emaout_kernel<<<64, 512, 0, stream>>>(embed_avg, ws, out);
}